// Round 2
// baseline (6908.424 us; speedup 1.0000x reference)
//
#include <hip/hip_runtime.h>
#include <hip/hip_bf16.h>

typedef __attribute__((ext_vector_type(8))) short short8;
typedef __attribute__((ext_vector_type(4))) float floatx4;

#define BB 2048   // batch
#define SS 24     // seq len (src and tgt)
#define HH 1024   // hidden
#define VV 37     // vocab
#define EE 256    // embed
#define G4H 4096  // 4*H gates

__device__ __forceinline__ unsigned short f2bf(float f) {
    union { float f; unsigned u; } x; x.f = f;
    unsigned r = x.u + 0x7FFF + ((x.u >> 16) & 1);   // RNE
    return (unsigned short)(r >> 16);
}
__device__ __forceinline__ float bf2f(unsigned short s) {
    union { unsigned u; float f; } x; x.u = ((unsigned)s) << 16; return x.f;
}
__device__ __forceinline__ float sigm(float x) {
    x = fminf(fmaxf(x, -15.f), 15.f);
    return 1.f / (1.f + __expf(-x));
}
__device__ __forceinline__ float tanh_(float x) {
    x = fminf(fmaxf(x, -15.f), 15.f);
    float e = __expf(2.f * x);
    return (e - 1.f) / (e + 1.f);
}

// ---------------- fp32 -> bf16 conversion (weights, emb) ----------------
__global__ __launch_bounds__(256)
void cvt_f2b_kernel(const float* __restrict__ s, unsigned short* __restrict__ d, int n4) {
    int i = blockIdx.x * 256 + threadIdx.x;
    if (i >= n4) return;
    float4 v = reinterpret_cast<const float4*>(s)[i];
    ushort4 o;
    o.x = f2bf(v.x); o.y = f2bf(v.y); o.z = f2bf(v.z); o.w = f2bf(v.w);
    reinterpret_cast<ushort4*>(d)[i] = o;
}

// ---------------- zero init (h0,h1 bf16 + c0,c1 fp32 region, 24 MiB) ----------------
__global__ __launch_bounds__(256) void zero16_kernel(uint4* __restrict__ p) {
    uint4 z; z.x = 0; z.y = 0; z.z = 0; z.w = 0;
    p[(size_t)blockIdx.x * 256 + threadIdx.x] = z;
}

// ---------------- token matrix [2,S,B]: enc tokens + shifted dec tokens ----------------
__global__ __launch_bounds__(256)
void tok_kernel(const int* __restrict__ src, const int* __restrict__ tgt, int* __restrict__ toks) {
    int idx = blockIdx.x * 256 + threadIdx.x;   // 2*24*2048 = 98304
    int b  = idx & 2047;
    int st = idx >> 11;          // 0..47
    int tok;
    if (st < SS) {               // encoder step st
        tok = src[b * SS + st];
    } else {                     // decoder step st-24, teacher forcing: [SOS, tgt[:,:-1]]
        int t = st - SS;
        tok = (t == 0) ? 1 : tgt[b * SS + (t - 1)];
    }
    toks[idx] = tok;
}

// ---------------- per-layer bias sums (fp32): b_ih + b_hh ----------------
__global__ __launch_bounds__(256) void bias_sum_kernel(
        const float* e0i, const float* e0h, const float* e1i, const float* e1h,
        const float* d0i, const float* d0h, const float* d1i, const float* d1h,
        float* __restrict__ out) {
    int idx = blockIdx.x * 256 + threadIdx.x;   // 4*4096
    int layer = idx >> 12, j = idx & 4095;
    const float* pi; const float* ph;
    switch (layer) {
        case 0:  pi = e0i; ph = e0h; break;
        case 1:  pi = e1i; ph = e1h; break;
        case 2:  pi = d0i; ph = d0h; break;
        default: pi = d1i; ph = d1h; break;
    }
    out[idx] = pi[j] + ph[j];
}

// ---------------- MFMA gate GEMM ----------------
// C[2048,4096] = A0[2048,K0] @ B0[4096,K0]^T + A1[2048,K1] @ B1[4096,K1]^T + bias
// If tok != nullptr, A1 rows are gathered: row r uses A1 + tok[m0+r]*K1 (embedding lookup).
// 128x128 block tile, BK=32, 4 waves each computing 64x64 via 4x4 mfma_f32_16x16x32_bf16.
// LDS fragment-contiguous: elem(tile16, lane, j) at ((tile*64+lane)*8+j) -> lane-linear ds_read_b128.
__global__ __launch_bounds__(256, 2)
void lstm_gate_gemm(const unsigned short* __restrict__ A0, const unsigned short* __restrict__ B0, int K0,
                    const unsigned short* __restrict__ A1, const unsigned short* __restrict__ B1, int K1,
                    const int* __restrict__ tok,
                    const float* __restrict__ bias, float* __restrict__ C) {
    __shared__ __align__(16) unsigned short As[4096];
    __shared__ __align__(16) unsigned short Bs[4096];
    const int tid  = threadIdx.x;
    const int lane = tid & 63;
    const int wave = tid >> 6;
    const int wm = wave >> 1, wn = wave & 1;
    const int m0 = blockIdx.y * 128;
    const int n0 = blockIdx.x * 128;

    floatx4 acc[4][4];
#pragma unroll
    for (int i = 0; i < 4; ++i)
#pragma unroll
        for (int j = 0; j < 4; ++j)
            acc[i][j] = (floatx4){0.f, 0.f, 0.f, 0.f};

    const int srow = tid >> 2;   // 0..63
    const int sq   = tid & 3;    // k-octet

    for (int seg = 0; seg < 2; ++seg) {
        const unsigned short* A = seg ? A1 : A0;
        const unsigned short* B = seg ? B1 : B0;
        const int    K = seg ? K1 : K0;
        const bool gather = (seg == 1) && (tok != nullptr);
        for (int kc = 0; kc < K; kc += 32) {
#pragma unroll
            for (int c = 0; c < 2; ++c) {
                const int row  = srow + c * 64;
                const int lidx = (((row >> 4) << 6) + (sq << 4) + (row & 15)) << 3;
                size_t arow = gather ? (size_t)tok[m0 + row] * K : (size_t)(m0 + row) * K;
                uint4 va = *reinterpret_cast<const uint4*>(A + arow + kc + sq * 8);
                uint4 vb = *reinterpret_cast<const uint4*>(B + (size_t)(n0 + row) * K + kc + sq * 8);
                *reinterpret_cast<uint4*>(&As[lidx]) = va;
                *reinterpret_cast<uint4*>(&Bs[lidx]) = vb;
            }
            __syncthreads();
            short8 af[4], bfr[4];
#pragma unroll
            for (int i = 0; i < 4; ++i) {
                af[i]  = *reinterpret_cast<const short8*>(&As[((((wm << 2) + i) << 6) + lane) << 3]);
                bfr[i] = *reinterpret_cast<const short8*>(&Bs[((((wn << 2) + i) << 6) + lane) << 3]);
            }
#pragma unroll
            for (int i = 0; i < 4; ++i)
#pragma unroll
                for (int j = 0; j < 4; ++j)
                    acc[i][j] = __builtin_amdgcn_mfma_f32_16x16x32_bf16(af[i], bfr[j], acc[i][j], 0, 0, 0);
            __syncthreads();
        }
    }

    // epilogue: C/D layout col=lane&15, row=quad*4+reg  [m89-verified]
    const int r = lane & 15, q = lane >> 4;
#pragma unroll
    for (int j = 0; j < 4; ++j) {
        const int col = n0 + wn * 64 + j * 16 + r;
        const float bv = bias[col];
#pragma unroll
        for (int i = 0; i < 4; ++i) {
#pragma unroll
            for (int p = 0; p < 4; ++p) {
                const int rowg = m0 + wm * 64 + i * 16 + q * 4 + p;
                C[(size_t)rowg * G4H + col] = acc[i][j][p] + bv;
            }
        }
    }
}

// ---------------- LSTM cell: gates -> (h bf16, c fp32) ----------------
__global__ __launch_bounds__(256)
void lstm_cell_kernel(const float* __restrict__ G, float* __restrict__ c,
                      unsigned short* __restrict__ h) {
    int e = blockIdx.x * 256 + threadIdx.x;   // B*H
    int b = e >> 10, j = e & 1023;
    size_t base = (size_t)b * G4H + j;
    float iv = sigm(G[base]);
    float fv = sigm(G[base + 1024]);
    float gv = tanh_(G[base + 2048]);
    float ov = sigm(G[base + 3072]);
    float cc = fv * c[e] + iv * gv;
    c[e] = cc;
    h[e] = f2bf(ov * tanh_(cc));
}

// ---------------- FC head, one timestep: out[b,t,:] = h1[b,:] @ fcW^T + fcb (fp32 out) ----------------
__global__ __launch_bounds__(256)
void fc_step_kernel(const unsigned short* __restrict__ h1, const unsigned short* __restrict__ fcW,
                    const float* __restrict__ fcb,
                    float* __restrict__ out, int t) {
    int b    = (blockIdx.x * 256 + threadIdx.x) >> 6;  // one wave per batch row
    int lane = threadIdx.x & 63;
    if (lane >= VV) return;
    const unsigned short* hrow = h1 + (size_t)b * HH;
    const unsigned short* wrow = fcW + (size_t)lane * HH;
    float acc = fcb[lane];
#pragma unroll 4
    for (int k8 = 0; k8 < HH / 8; ++k8) {
        short8 hv = *reinterpret_cast<const short8*>(hrow + k8 * 8);
        short8 wv = *reinterpret_cast<const short8*>(wrow + k8 * 8);
#pragma unroll
        for (int u = 0; u < 8; ++u)
            acc += bf2f((unsigned short)hv[u]) * bf2f((unsigned short)wv[u]);
    }
    out[(size_t)b * (SS * VV) + t * VV + lane] = acc;
}

extern "C" void kernel_launch(void* const* d_in, const int* in_sizes, int n_in,
                              void* d_out, int out_size, void* d_ws, size_t ws_size,
                              hipStream_t stream) {
    const int*   src    = (const int*)d_in[0];
    const int*   tgt    = (const int*)d_in[1];
    const float* emb    = (const float*)d_in[2];
    const float* eW_ih0 = (const float*)d_in[3];
    const float* eW_hh0 = (const float*)d_in[4];
    const float* eb_ih0 = (const float*)d_in[5];
    const float* eb_hh0 = (const float*)d_in[6];
    const float* eW_ih1 = (const float*)d_in[7];
    const float* eW_hh1 = (const float*)d_in[8];
    const float* eb_ih1 = (const float*)d_in[9];
    const float* eb_hh1 = (const float*)d_in[10];
    const float* dW_ih0 = (const float*)d_in[11];
    const float* dW_hh0 = (const float*)d_in[12];
    const float* db_ih0 = (const float*)d_in[13];
    const float* db_hh0 = (const float*)d_in[14];
    const float* dW_ih1 = (const float*)d_in[15];
    const float* dW_hh1 = (const float*)d_in[16];
    const float* db_ih1 = (const float*)d_in[17];
    const float* db_hh1 = (const float*)d_in[18];
    const float* fcW    = (const float*)d_in[19];
    const float* fcb    = (const float*)d_in[20];
    float* out = (float*)d_out;

    // ---- workspace layout (256B aligned; all sizes are multiples of 256B) ----
    char* w = (char*)d_ws;
    size_t off = 0;
    auto walloc = [&](size_t bytes) { void* p = w + off; off += (bytes + 255) & ~(size_t)255; return p; };
    // bf16 weight copies
    unsigned short* bW[8];
    const float* srcW[8] = {eW_ih0, eW_hh0, eW_ih1, eW_hh1, dW_ih0, dW_hh0, dW_ih1, dW_hh1};
    const int     szW[8] = {G4H*EE, G4H*HH, G4H*HH, G4H*HH, G4H*EE, G4H*HH, G4H*HH, G4H*HH};
    for (int i = 0; i < 8; ++i) bW[i] = (unsigned short*)walloc((size_t)szW[i] * 2);
    unsigned short* bfcW = (unsigned short*)walloc((size_t)VV * HH * 2);
    unsigned short* bemb = (unsigned short*)walloc((size_t)VV * EE * 2);
    // states: h0,h1 (bf16), c0,c1 (fp32) — contiguous 24 MiB zero region
    unsigned short* h0 = (unsigned short*)walloc((size_t)BB * HH * 2);
    unsigned short* h1 = (unsigned short*)walloc((size_t)BB * HH * 2);
    float* c0 = (float*)walloc((size_t)BB * HH * 4);
    float* c1 = (float*)walloc((size_t)BB * HH * 4);
    float* G    = (float*)walloc((size_t)BB * G4H * 4);
    float* bsum = (float*)walloc((size_t)4 * G4H * 4);
    int*   toks = (int*)walloc((size_t)2 * SS * BB * 4);

    // ---- weight/emb conversion fp32 -> bf16 ----
    for (int i = 0; i < 8; ++i) {
        int n4 = szW[i] / 4;
        cvt_f2b_kernel<<<(n4 + 255) / 256, 256, 0, stream>>>(srcW[i], bW[i], n4);
    }
    cvt_f2b_kernel<<<(VV * HH / 4 + 255) / 256, 256, 0, stream>>>(fcW, bfcW, VV * HH / 4);
    cvt_f2b_kernel<<<(VV * EE / 4 + 255) / 256, 256, 0, stream>>>(emb, bemb, VV * EE / 4);

    // zero h0,h1,c0,c1 (contiguous 25,165,824 B = 1,572,864 uint4)
    zero16_kernel<<<6144, 256, 0, stream>>>((uint4*)h0);
    bias_sum_kernel<<<64, 256, 0, stream>>>(eb_ih0, eb_hh0, eb_ih1, eb_hh1,
                                            db_ih0, db_hh0, db_ih1, db_hh1, bsum);
    tok_kernel<<<384, 256, 0, stream>>>(src, tgt, toks);

    dim3 ggrid(G4H / 128, BB / 128);   // (32, 16)

    // ---- encoder: interleaved layer0/layer1 per timestep ----
    for (int t = 0; t < SS; ++t) {
        lstm_gate_gemm<<<ggrid, 256, 0, stream>>>(
            h0, bW[1], HH,            // h-part: h0 @ eW_hh0^T
            bemb, bW[0], EE,          // x-part: emb[tok] @ eW_ih0^T (gathered)
            toks + (size_t)t * BB,
            bsum + 0 * G4H, G);
        lstm_cell_kernel<<<8192, 256, 0, stream>>>(G, c0, h0);
        lstm_gate_gemm<<<ggrid, 256, 0, stream>>>(
            h1, bW[3], HH,            // h-part: h1 @ eW_hh1^T
            h0, bW[2], HH,            // x-part: h0 @ eW_ih1^T
            nullptr,
            bsum + 1 * G4H, G);
        lstm_cell_kernel<<<8192, 256, 0, stream>>>(G, c1, h1);
    }

    // ---- decoder (initial state = encoder final state, already in h/c buffers) ----
    for (int t = 0; t < SS; ++t) {
        lstm_gate_gemm<<<ggrid, 256, 0, stream>>>(
            h0, bW[5], HH,            // h0 @ dW_hh0^T
            bemb, bW[4], EE,          // emb[dec_tok] @ dW_ih0^T
            toks + (size_t)(SS + t) * BB,
            bsum + 2 * G4H, G);
        lstm_cell_kernel<<<8192, 256, 0, stream>>>(G, c0, h0);
        lstm_gate_gemm<<<ggrid, 256, 0, stream>>>(
            h1, bW[7], HH,            // h1 @ dW_hh1^T
            h0, bW[6], HH,            // h0 @ dW_ih1^T
            nullptr,
            bsum + 3 * G4H, G);
        lstm_cell_kernel<<<8192, 256, 0, stream>>>(G, c1, h1);
        fc_step_kernel<<<512, 256, 0, stream>>>(h1, bfcW, fcb, out, t);
    }
}

// Round 3
// 6562.968 us; speedup vs baseline: 1.0526x; 1.0526x over previous
//
#include <hip/hip_runtime.h>
#include <hip/hip_bf16.h>

typedef __attribute__((ext_vector_type(8))) short short8;
typedef __attribute__((ext_vector_type(4))) float floatx4;

#define BB 2048   // batch
#define SS 24     // seq len (src and tgt)
#define HH 1024   // hidden
#define VV 37     // vocab
#define EE 256    // embed
#define G4H 4096  // 4*H gates

__device__ __forceinline__ unsigned short f2bf(float f) {
    union { float f; unsigned u; } x; x.f = f;
    unsigned r = x.u + 0x7FFF + ((x.u >> 16) & 1);   // RNE
    return (unsigned short)(r >> 16);
}
__device__ __forceinline__ float bf2f(unsigned short s) {
    union { unsigned u; float f; } x; x.u = ((unsigned)s) << 16; return x.f;
}
__device__ __forceinline__ float sigm(float x) {
    x = fminf(fmaxf(x, -15.f), 15.f);
    return 1.f / (1.f + __expf(-x));
}
__device__ __forceinline__ float tanh_(float x) {
    x = fminf(fmaxf(x, -15.f), 15.f);
    float e = __expf(2.f * x);
    return (e - 1.f) / (e + 1.f);
}

// async global->LDS DMA, 16B per lane; LDS dest = wave-uniform base + lane*16 [m97/m104]
typedef const __attribute__((address_space(1))) void* gas_t;
typedef __attribute__((address_space(3))) void* las_t;
__device__ __forceinline__ void gl_lds16(const void* g, void* l) {
    __builtin_amdgcn_global_load_lds((gas_t)g, (las_t)l, 16, 0, 0);
}

// ---------------- fp32 -> bf16 plain conversion (fcW, emb) ----------------
__global__ __launch_bounds__(256)
void cvt_f2b_kernel(const float* __restrict__ s, unsigned short* __restrict__ d, int n4) {
    int i = blockIdx.x * 256 + threadIdx.x;
    if (i >= n4) return;
    float4 v = reinterpret_cast<const float4*>(s)[i];
    ushort4 o;
    o.x = f2bf(v.x); o.y = f2bf(v.y); o.z = f2bf(v.z); o.w = f2bf(v.w);
    reinterpret_cast<ushort4*>(d)[i] = o;
}

// ------- fp32 -> bf16 with gate interleave: out row u*4+g <- in row g*1024+u -------
__global__ __launch_bounds__(256)
void cvt_perm_kernel(const float* __restrict__ s, unsigned short* __restrict__ d, int kqshift) {
    int i = blockIdx.x * 256 + threadIdx.x;     // over 4096 * K/4 float4 groups
    int kq = 1 << kqshift;
    int r  = i >> kqshift;                      // out row 0..4095
    int kk = i & (kq - 1);
    int u = r >> 2, g = r & 3;
    float4 v = reinterpret_cast<const float4*>(s)[(size_t)((g << 10) + u) * kq + kk];
    ushort4 o;
    o.x = f2bf(v.x); o.y = f2bf(v.y); o.z = f2bf(v.z); o.w = f2bf(v.w);
    reinterpret_cast<ushort4*>(d)[(size_t)i] = o;
}

// ---------------- zero init (h0a,h1a bf16 + c0,c1 fp32 region, 24 MiB) ----------------
__global__ __launch_bounds__(256) void zero16_kernel(uint4* __restrict__ p) {
    uint4 z; z.x = 0; z.y = 0; z.z = 0; z.w = 0;
    p[(size_t)blockIdx.x * 256 + threadIdx.x] = z;
}

// ---------------- token matrix [2,S,B] ----------------
__global__ __launch_bounds__(256)
void tok_kernel(const int* __restrict__ src, const int* __restrict__ tgt, int* __restrict__ toks) {
    int idx = blockIdx.x * 256 + threadIdx.x;   // 2*24*2048
    int b  = idx & 2047;
    int st = idx >> 11;
    int tok;
    if (st < SS) tok = src[b * SS + st];
    else { int t = st - SS; tok = (t == 0) ? 1 : tgt[b * SS + (t - 1)]; }
    toks[idx] = tok;
}

// ---------------- per-layer bias sums, gate-interleaved ----------------
__global__ __launch_bounds__(256) void bias_sum_kernel(
        const float* e0i, const float* e0h, const float* e1i, const float* e1h,
        const float* d0i, const float* d0h, const float* d1i, const float* d1h,
        float* __restrict__ out) {
    int idx = blockIdx.x * 256 + threadIdx.x;   // 4*4096
    int layer = idx >> 12, jj = idx & 4095;
    int u = jj >> 2, g = jj & 3;
    int src_j = (g << 10) + u;
    const float* pi; const float* ph;
    switch (layer) {
        case 0:  pi = e0i; ph = e0h; break;
        case 1:  pi = e1i; ph = e1h; break;
        case 2:  pi = d0i; ph = d0h; break;
        default: pi = d1i; ph = d1h; break;
    }
    out[idx] = pi[src_j] + ph[src_j];
}

// ---------------- fused LSTM step: gates GEMM + cell ----------------
// gates[2048,4096] = A0 @ W0^T + A1 @ W1^T + bias   (W rows gate-interleaved: row = 4u+g)
// then per (batch row, hidden unit): c = f*c + i*g ; h = o*tanh(c)
// A1 rows gathered via tok if tok != nullptr (embedding lookup).
// 128x128 tile, BK=32, 4 waves x (4x4) mfma_f32_16x16x32_bf16, global_load_lds staging.
__global__ __launch_bounds__(256, 2)
void lstm_step_gemm(const unsigned short* __restrict__ A0, const unsigned short* __restrict__ W0, int K0,
                    const unsigned short* __restrict__ A1, const unsigned short* __restrict__ W1, int K1,
                    const int* __restrict__ tok,
                    const float* __restrict__ bias,
                    float* __restrict__ c, unsigned short* __restrict__ hout) {
    __shared__ __align__(16) unsigned char smem[65536];
    unsigned short* As = (unsigned short*)smem;            // 8 KB (8 tiles x 512 shorts)
    unsigned short* Bs = (unsigned short*)(smem + 8192);   // 8 KB
    float* Gs = (float*)smem;                              // 64 KB, reused after K-loop

    const int tid  = threadIdx.x;
    const int lane = tid & 63;
    const int wave = tid >> 6;
    const int wm = wave >> 1, wn = wave & 1;
    const int m0 = blockIdx.y * 128;
    const int n0 = blockIdx.x * 128;

    floatx4 acc[4][4];
#pragma unroll
    for (int i = 0; i < 4; ++i)
#pragma unroll
        for (int j = 0; j < 4; ++j)
            acc[i][j] = (floatx4){0.f, 0.f, 0.f, 0.f};

    const int r16  = lane & 15;          // row within 16-row tile
    const int koff = (lane >> 4) << 3;   // k-octet offset (elements)
    const int tA0 = wave, tA1 = wave + 4;

#pragma unroll
    for (int seg = 0; seg < 2; ++seg) {
        const unsigned short* A = seg ? A1 : A0;
        const unsigned short* W = seg ? W1 : W0;
        const int K = seg ? K1 : K0;
        size_t a0, a1;
        if (seg == 1 && tok != nullptr) {
            a0 = (size_t)tok[m0 + tA0 * 16 + r16] * K + koff;
            a1 = (size_t)tok[m0 + tA1 * 16 + r16] * K + koff;
        } else {
            a0 = (size_t)(m0 + tA0 * 16 + r16) * K + koff;
            a1 = (size_t)(m0 + tA1 * 16 + r16) * K + koff;
        }
        const size_t b0 = (size_t)(n0 + tA0 * 16 + r16) * K + koff;
        const size_t b1 = (size_t)(n0 + tA1 * 16 + r16) * K + koff;

        for (int kc = 0; kc < K; kc += 32) {
            gl_lds16(A + a0 + kc, As + (tA0 << 9));
            gl_lds16(A + a1 + kc, As + (tA1 << 9));
            gl_lds16(W + b0 + kc, Bs + (tA0 << 9));
            gl_lds16(W + b1 + kc, Bs + (tA1 << 9));
            __syncthreads();
            short8 af[4], bfr[4];
#pragma unroll
            for (int i = 0; i < 4; ++i) {
                af[i]  = *reinterpret_cast<const short8*>(As + ((((wm << 2) + i) << 9) + (lane << 3)));
                bfr[i] = *reinterpret_cast<const short8*>(Bs + ((((wn << 2) + i) << 9) + (lane << 3)));
            }
#pragma unroll
            for (int i = 0; i < 4; ++i)
#pragma unroll
                for (int j = 0; j < 4; ++j)
                    acc[i][j] = __builtin_amdgcn_mfma_f32_16x16x32_bf16(af[i], bfr[j], acc[i][j], 0, 0, 0);
            __syncthreads();   // also protects Gs overwrite after the final chunk
        }
    }

    // ---- epilogue 1: acc + bias -> Gs[row][col] (block-local 128x128 fp32) ----
    const int rl = lane & 15, q = lane >> 4;
#pragma unroll
    for (int j = 0; j < 4; ++j) {
        const int col = wn * 64 + j * 16 + rl;
        const float bv = bias[n0 + col];
#pragma unroll
        for (int i = 0; i < 4; ++i) {
#pragma unroll
            for (int p = 0; p < 4; ++p) {
                const int row = wm * 64 + i * 16 + q * 4 + p;
                Gs[row * 128 + col] = acc[i][j][p] + bv;
            }
        }
    }
    __syncthreads();

    // ---- epilogue 2: LSTM cell. cols 4u..4u+3 = (i,f,g,o) of unit u ----
    const int u     = tid & 31;                 // 32 units per block
    const int rbase = (tid >> 5) << 4;          // 8 groups x 16 rows
    const int ucol  = (n0 >> 2) + u;            // global hidden unit
#pragma unroll
    for (int rr = 0; rr < 16; ++rr) {
        const int row = rbase + rr;
        float4 g4 = *reinterpret_cast<const float4*>(Gs + row * 128 + (u << 2));
        float iv = sigm(g4.x);
        float fv = sigm(g4.y);
        float gv = tanh_(g4.z);
        float ov = sigm(g4.w);
        const size_t ci = (size_t)(m0 + row) * HH + ucol;
        float cc = fv * c[ci] + iv * gv;
        c[ci] = cc;
        hout[ci] = f2bf(ov * tanh_(cc));
    }
}

// ---------------- FC head, one timestep ----------------
__global__ __launch_bounds__(256)
void fc_step_kernel(const unsigned short* __restrict__ h1, const unsigned short* __restrict__ fcW,
                    const float* __restrict__ fcb,
                    float* __restrict__ out, int t) {
    int b    = (blockIdx.x * 256 + threadIdx.x) >> 6;
    int lane = threadIdx.x & 63;
    if (lane >= VV) return;
    const unsigned short* hrow = h1 + (size_t)b * HH;
    const unsigned short* wrow = fcW + (size_t)lane * HH;
    float acc = fcb[lane];
#pragma unroll 4
    for (int k8 = 0; k8 < HH / 8; ++k8) {
        short8 hv = *reinterpret_cast<const short8*>(hrow + k8 * 8);
        short8 wv = *reinterpret_cast<const short8*>(wrow + k8 * 8);
#pragma unroll
        for (int uu = 0; uu < 8; ++uu)
            acc += bf2f((unsigned short)hv[uu]) * bf2f((unsigned short)wv[uu]);
    }
    out[(size_t)b * (SS * VV) + t * VV + lane] = acc;
}

extern "C" void kernel_launch(void* const* d_in, const int* in_sizes, int n_in,
                              void* d_out, int out_size, void* d_ws, size_t ws_size,
                              hipStream_t stream) {
    const int*   src    = (const int*)d_in[0];
    const int*   tgt    = (const int*)d_in[1];
    const float* emb    = (const float*)d_in[2];
    const float* eW_ih0 = (const float*)d_in[3];
    const float* eW_hh0 = (const float*)d_in[4];
    const float* eb_ih0 = (const float*)d_in[5];
    const float* eb_hh0 = (const float*)d_in[6];
    const float* eW_ih1 = (const float*)d_in[7];
    const float* eW_hh1 = (const float*)d_in[8];
    const float* eb_ih1 = (const float*)d_in[9];
    const float* eb_hh1 = (const float*)d_in[10];
    const float* dW_ih0 = (const float*)d_in[11];
    const float* dW_hh0 = (const float*)d_in[12];
    const float* db_ih0 = (const float*)d_in[13];
    const float* db_hh0 = (const float*)d_in[14];
    const float* dW_ih1 = (const float*)d_in[15];
    const float* dW_hh1 = (const float*)d_in[16];
    const float* db_ih1 = (const float*)d_in[17];
    const float* db_hh1 = (const float*)d_in[18];
    const float* fcW    = (const float*)d_in[19];
    const float* fcb    = (const float*)d_in[20];
    float* out = (float*)d_out;

    // ---- workspace layout ----
    char* w = (char*)d_ws;
    size_t off = 0;
    auto walloc = [&](size_t bytes) { void* p = w + off; off += (bytes + 255) & ~(size_t)255; return p; };
    unsigned short* bW[8];
    const float* srcW[8] = {eW_ih0, eW_hh0, eW_ih1, eW_hh1, dW_ih0, dW_hh0, dW_ih1, dW_hh1};
    const int     szW[8] = {G4H*EE, G4H*HH, G4H*HH, G4H*HH, G4H*EE, G4H*HH, G4H*HH, G4H*HH};
    for (int i = 0; i < 8; ++i) bW[i] = (unsigned short*)walloc((size_t)szW[i] * 2);
    unsigned short* bfcW = (unsigned short*)walloc((size_t)VV * HH * 2);
    unsigned short* bemb = (unsigned short*)walloc((size_t)VV * EE * 2);
    // zero region: h0a, h1a (bf16) + c0, c1 (fp32) — contiguous 24 MiB
    unsigned short* h0a = (unsigned short*)walloc((size_t)BB * HH * 2);
    unsigned short* h1a = (unsigned short*)walloc((size_t)BB * HH * 2);
    float* c0 = (float*)walloc((size_t)BB * HH * 4);
    float* c1 = (float*)walloc((size_t)BB * HH * 4);
    unsigned short* h0b = (unsigned short*)walloc((size_t)BB * HH * 2);
    unsigned short* h1b = (unsigned short*)walloc((size_t)BB * HH * 2);
    float* bsum = (float*)walloc((size_t)4 * G4H * 4);
    int*   toks = (int*)walloc((size_t)2 * SS * BB * 4);

    unsigned short* h0[2] = {h0a, h0b};
    unsigned short* h1[2] = {h1a, h1b};

    // ---- setup: weight conversion (gate-interleaved), biases, tokens, zeros ----
    for (int i = 0; i < 8; ++i) {
        int kqshift = (szW[i] == G4H * EE) ? 6 : 8;     // K/4 = 64 or 256
        int n4 = szW[i] / 4;
        cvt_perm_kernel<<<n4 / 256, 256, 0, stream>>>(srcW[i], bW[i], kqshift);
    }
    cvt_f2b_kernel<<<(VV * HH / 4 + 255) / 256, 256, 0, stream>>>(fcW, bfcW, VV * HH / 4);
    cvt_f2b_kernel<<<(VV * EE / 4 + 255) / 256, 256, 0, stream>>>(emb, bemb, VV * EE / 4);
    zero16_kernel<<<6144, 256, 0, stream>>>((uint4*)h0a);
    bias_sum_kernel<<<64, 256, 0, stream>>>(eb_ih0, eb_hh0, eb_ih1, eb_hh1,
                                            db_ih0, db_hh0, db_ih1, db_hh1, bsum);
    tok_kernel<<<384, 256, 0, stream>>>(src, tgt, toks);

    dim3 ggrid(G4H / 128, BB / 128);   // (32, 16) = 512 blocks

    int p = 0;
    // ---- encoder ----
    for (int t = 0; t < SS; ++t) {
        lstm_step_gemm<<<ggrid, 256, 0, stream>>>(
            h0[p], bW[1], HH, bemb, bW[0], EE, toks + (size_t)t * BB,
            bsum + 0 * G4H, c0, h0[p ^ 1]);
        lstm_step_gemm<<<ggrid, 256, 0, stream>>>(
            h1[p], bW[3], HH, h0[p ^ 1], bW[2], HH, nullptr,
            bsum + 1 * G4H, c1, h1[p ^ 1]);
        p ^= 1;
    }
    // ---- decoder ----
    for (int t = 0; t < SS; ++t) {
        lstm_step_gemm<<<ggrid, 256, 0, stream>>>(
            h0[p], bW[5], HH, bemb, bW[4], EE, toks + (size_t)(SS + t) * BB,
            bsum + 2 * G4H, c0, h0[p ^ 1]);
        lstm_step_gemm<<<ggrid, 256, 0, stream>>>(
            h1[p], bW[7], HH, h0[p ^ 1], bW[6], HH, nullptr,
            bsum + 3 * G4H, c1, h1[p ^ 1]);
        fc_step_kernel<<<512, 256, 0, stream>>>(h1[p ^ 1], bfcW, fcb, out, t);
        p ^= 1;
    }
}